// Round 2
// baseline (795.322 us; speedup 1.0000x reference)
//
#include <hip/hip_runtime.h>
#include <hip/hip_bf16.h>

typedef __attribute__((ext_vector_type(4)))  float  f32x4;
typedef __attribute__((ext_vector_type(16))) float  f32x16;
typedef __attribute__((ext_vector_type(4)))  float  floatv4;
typedef __attribute__((ext_vector_type(8)))  short  short8;
typedef __attribute__((ext_vector_type(8)))  __bf16 bf16x8;

#define NB 2
#define NS 2048
#define ND 1024
#define NH 16
#define NHD 64
#define NM (NB*NS)
// (1/8) * log2(e): folds both the attention scale and the exp->exp2 base change into Q
#define Q_SCALE 0.18033688011112042f

#if __has_builtin(__builtin_amdgcn_exp2f)
#define EXP2(x) __builtin_amdgcn_exp2f(x)
#else
#define EXP2(x) exp2f(x)
#endif

static __device__ __forceinline__ unsigned short f2bf(float f) {
  unsigned int u = __builtin_bit_cast(unsigned int, f);
  u += 0x7fffu + ((u >> 16) & 1u);   // RNE; inputs are finite, no NaN handling needed
  return (unsigned short)(u >> 16);
}

static __device__ __forceinline__ f32x4 mfma16(short8 a, short8 b, f32x4 c) {
  return __builtin_amdgcn_mfma_f32_16x16x32_bf16(
      __builtin_bit_cast(bf16x8, a), __builtin_bit_cast(bf16x8, b), c, 0, 0, 0);
}
static __device__ __forceinline__ f32x16 mfma32(short8 a, short8 b, f32x16 c) {
  return __builtin_amdgcn_mfma_f32_32x32x16_bf16(
      __builtin_bit_cast(bf16x8, a), __builtin_bit_cast(bf16x8, b), c, 0, 0, 0);
}

static __device__ __forceinline__ f32x16 zero16() {
  f32x16 z;
#pragma unroll
  for (int i = 0; i < 16; ++i) z[i] = 0.f;
  return z;
}

// ---------------------------------------------------------------------------
// Weight transpose + bf16 convert: Wt[n][k] = bf16(W[k][n])
// ---------------------------------------------------------------------------
struct TWArgs { const float* W[4]; short* Wt[4]; };

__global__ __launch_bounds__(256) void wt_kernel(TWArgs args) {
  __shared__ float tile[32][33];
  const float* W = args.W[blockIdx.z];
  short* Wt = args.Wt[blockIdx.z];
  int k0 = blockIdx.x * 32, n0 = blockIdx.y * 32;
  int tx = threadIdx.x, ty = threadIdx.y;  // 32 x 8
#pragma unroll
  for (int i = 0; i < 4; ++i)
    tile[ty + 8 * i][tx] = W[(size_t)(k0 + ty + 8 * i) * ND + n0 + tx];
  __syncthreads();
#pragma unroll
  for (int i = 0; i < 4; ++i)
    Wt[(size_t)(n0 + ty + 8 * i) * ND + k0 + tx] = (short)f2bf(tile[tx][ty + 8 * i]);
}

// ---------------------------------------------------------------------------
// Projection GEMM: C[M=4096, N=1024] = A[4096,1024] @ W(K,N) + bias
// Wt given transposed bf16 [N][K]. BM=BN=128, BK=32, 4 waves (2x2), 16x16x32 MFMA.
// mode 0: bf16 out [B][H][S][HD] (Q/K layout), * scale after bias
// mode 1: bf16 out [B][H][HD][S] (V transposed layout)
// mode 2: f32 out flat [M][N]    (final output)
// ---------------------------------------------------------------------------
struct ProjArgs {
  const void* A[3]; const short* W[3]; const float* bias[3];
  void* out[3]; float scale[3]; int mode[3];
};

template<bool A_BF16>
__global__ __launch_bounds__(256, 3) void gemm_proj(ProjArgs args) {
  int z = blockIdx.y;
  const char* Abase = (const char*)args.A[z];
  const short* W = args.W[z];
  const float* bias = args.bias[z];
  float scale = args.scale[z];
  int mode = args.mode[z];

  __shared__ short As[128 * 32];
  __shared__ short Bs[128 * 32];
  int tid = threadIdx.x;
  int lane = tid & 63;
  int wave = tid >> 6;
  int wr = wave >> 1, wc = wave & 1;
  int m0 = (blockIdx.x >> 3) * 128;
  int n0 = (blockIdx.x & 7) * 128;

  int srow = tid >> 1, shalf = tid & 1;
  unsigned sbase = (unsigned)(srow * 64 + shalf * 32);
  unsigned ssw = ((unsigned)(srow & 7)) << 4;
  unsigned d1 = sbase ^ ssw, d2 = (sbase + 16u) ^ ssw;

  f32x4 acc[4][4];
#pragma unroll
  for (int i = 0; i < 4; ++i)
#pragma unroll
    for (int j = 0; j < 4; ++j) acc[i][j] = (f32x4){0.f, 0.f, 0.f, 0.f};

  for (int kt = 0; kt < 32; ++kt) {
    int k0 = kt * 32;
    // --- stage A tile (rows m0..m0+127, k0..k0+31) ---
    if (A_BF16) {
      const short* src = (const short*)Abase + (size_t)(m0 + srow) * ND + k0 + shalf * 16;
      short8 v0 = ((const short8*)src)[0];
      short8 v1 = ((const short8*)src)[1];
      *(short8*)((char*)As + d1) = v0;
      *(short8*)((char*)As + d2) = v1;
    } else {
      const float* src = (const float*)Abase + (size_t)(m0 + srow) * ND + k0 + shalf * 16;
      floatv4 f0 = ((const floatv4*)src)[0];
      floatv4 f1 = ((const floatv4*)src)[1];
      floatv4 f2 = ((const floatv4*)src)[2];
      floatv4 f3 = ((const floatv4*)src)[3];
      short8 v0, v1;
#pragma unroll
      for (int j = 0; j < 4; ++j) { v0[j] = (short)f2bf(f0[j]); v0[4 + j] = (short)f2bf(f1[j]); }
#pragma unroll
      for (int j = 0; j < 4; ++j) { v1[j] = (short)f2bf(f2[j]); v1[4 + j] = (short)f2bf(f3[j]); }
      *(short8*)((char*)As + d1) = v0;
      *(short8*)((char*)As + d2) = v1;
    }
    // --- stage B tile (Wt rows n0..n0+127, k0..k0+31) ---
    {
      const short* src = W + (size_t)(n0 + srow) * ND + k0 + shalf * 16;
      short8 v0 = ((const short8*)src)[0];
      short8 v1 = ((const short8*)src)[1];
      *(short8*)((char*)Bs + d1) = v0;
      *(short8*)((char*)Bs + d2) = v1;
    }
    __syncthreads();

    short8 af[4], bfr[4];
#pragma unroll
    for (int i = 0; i < 4; ++i) {
      int row = wr * 64 + i * 16 + (lane & 15);
      unsigned bo = ((unsigned)(row * 64 + (lane >> 4) * 16)) ^ (((unsigned)(row & 7)) << 4);
      af[i] = *(const short8*)((const char*)As + bo);
      int col = wc * 64 + i * 16 + (lane & 15);
      unsigned bo2 = ((unsigned)(col * 64 + (lane >> 4) * 16)) ^ (((unsigned)(col & 7)) << 4);
      bfr[i] = *(const short8*)((const char*)Bs + bo2);
    }
#pragma unroll
    for (int i = 0; i < 4; ++i)
#pragma unroll
      for (int j = 0; j < 4; ++j)
        acc[i][j] = mfma16(af[i], bfr[j], acc[i][j]);
    __syncthreads();
  }

  // --- epilogue ---
#pragma unroll
  for (int j = 0; j < 4; ++j) {
    int n = n0 + wc * 64 + j * 16 + (lane & 15);
    float bv = bias[n];
#pragma unroll
    for (int i = 0; i < 4; ++i) {
#pragma unroll
      for (int r = 0; r < 4; ++r) {
        int m = m0 + wr * 64 + i * 16 + (lane >> 4) * 4 + r;
        float v = (acc[i][j][r] + bv) * scale;
        if (mode == 2) {
          ((float*)args.out[z])[(size_t)m * ND + n] = v;
        } else {
          int b = m >> 11, s = m & 2047, h = n >> 6, d = n & 63;
          size_t idx = (mode == 0)
                           ? (((size_t)(b * NH + h) * NS + s) * NHD + d)
                           : (((size_t)(b * NH + h) * NHD + d) * NS + s);
          ((short*)args.out[z])[idx] = (short)f2bf(v);
        }
      }
    }
  }
}

// ---------------------------------------------------------------------------
// Fused attention: per WG (q-tile of 128 rows, one (b,h)); 4 waves x 32 q-rows.
// Sweep 1: e = exp2(Q.K'), rowsum, unnormalized PV (P via swizzled LDS transpose).
// Sweep 2: recompute scores, write p = e * inv_rowsum to attn output (512 MB, once).
// Q has (1/8)*log2e folded in at projection. Scores bounded -> no max subtraction.
// ---------------------------------------------------------------------------
__global__ __launch_bounds__(256, 2) void attn_kernel(
    const short* __restrict__ Qb, const short* __restrict__ Kb,
    const short* __restrict__ Vt, short* __restrict__ Cb,
    float* __restrict__ attnw) {
  __shared__ short Ks[64 * 64];
  __shared__ short Vs[64 * 64];
  __shared__ short Ps[4][32 * 64];
  int bh = blockIdx.y;
  int q0 = blockIdx.x * 128;
  int tid = threadIdx.x;
  int wave = tid >> 6, lane = tid & 63;
  int lo = lane & 31, hi = lane >> 5;
  const short* Qh = Qb + (size_t)bh * NS * NHD;
  const short* Kh = Kb + (size_t)bh * NS * NHD;
  const short* Vh = Vt + (size_t)bh * NHD * NS;
  int qw = q0 + wave * 32;

  short8 aq[4];
#pragma unroll
  for (int ks = 0; ks < 4; ++ks)
    aq[ks] = *(const short8*)(Qh + (size_t)(qw + lo) * NHD + ks * 16 + hi * 8);

  float rs[16];
#pragma unroll
  for (int r = 0; r < 16; ++r) rs[r] = 0.f;
  f32x16 c0 = zero16(), c1 = zero16();

  char* PsW = (char*)Ps[wave];

  auto stageKV = [&](int kt, bool withV) {
#pragma unroll
    for (int rr = 0; rr < 2; ++rr) {
      int c = rr * 256 + tid;            // 0..511 chunks of 16B
      int row = c >> 3, off = c & 7;
      unsigned dstb = ((unsigned)(row * 128 + off * 16)) ^ (((unsigned)(row & 7)) << 4);
      *(short8*)((char*)Ks + dstb) =
          *(const short8*)(Kh + (size_t)(kt * 64 + row) * NHD + off * 8);
      if (withV)
        *(short8*)((char*)Vs + dstb) =
            *(const short8*)(Vh + (size_t)row * NS + kt * 64 + off * 8);
    }
  };

  auto scores = [&](f32x16& s0, f32x16& s1) {
#pragma unroll
    for (int ks = 0; ks < 4; ++ks) {
      unsigned ko = (unsigned)(ks * 32 + hi * 16);
      unsigned sw = ((unsigned)(lo & 7)) << 4;
      short8 bk0 = *(const short8*)((const char*)Ks + (((unsigned)(lo * 128) + ko) ^ sw));
      short8 bk1 = *(const short8*)((const char*)Ks + (((unsigned)((lo + 32) * 128) + ko) ^ sw));
      s0 = mfma32(aq[ks], bk0, s0);
      s1 = mfma32(aq[ks], bk1, s1);
    }
  };

  // ---------------- Sweep 1 ----------------
  for (int kt = 0; kt < 32; ++kt) {
    stageKV(kt, true);
    __syncthreads();
    f32x16 s0 = zero16(), s1 = zero16();
    scores(s0, s1);
#pragma unroll
    for (int r = 0; r < 16; ++r) {
      float e0 = EXP2(s0[r]);
      float e1 = EXP2(s1[r]);
      rs[r] += e0 + e1;
      int qrow = (r & 3) + 8 * (r >> 2) + 4 * hi;
      unsigned sw = ((unsigned)(qrow & 7)) << 4;
      *(short*)(PsW + (((unsigned)(qrow * 128 + lo * 2)) ^ sw)) = (short)f2bf(e0);
      *(short*)(PsW + (((unsigned)(qrow * 128 + 64 + lo * 2)) ^ sw)) = (short)f2bf(e1);
    }
    asm volatile("s_waitcnt lgkmcnt(0)" ::: "memory");
    // PV: ctx += P * V  (A = P rows q, B = Vt rows d)
#pragma unroll
    for (int kk = 0; kk < 4; ++kk) {
      unsigned ko = (unsigned)(kk * 32 + hi * 16);
      unsigned sw = ((unsigned)(lo & 7)) << 4;
      short8 ap = *(const short8*)(PsW + (((unsigned)(lo * 128) + ko) ^ sw));
      short8 bv0 = *(const short8*)((const char*)Vs + (((unsigned)(lo * 128) + ko) ^ sw));
      short8 bv1 = *(const short8*)((const char*)Vs + (((unsigned)((lo + 32) * 128) + ko) ^ sw));
      c0 = mfma32(ap, bv0, c0);
      c1 = mfma32(ap, bv1, c1);
    }
    __syncthreads();
  }

  // rowsum reduce across the 32 lanes sharing the same q-row set
#pragma unroll
  for (int r = 0; r < 16; ++r) {
    float v = rs[r];
    v += __shfl_xor(v, 1);
    v += __shfl_xor(v, 2);
    v += __shfl_xor(v, 4);
    v += __shfl_xor(v, 8);
    v += __shfl_xor(v, 16);
    rs[r] = v;
  }
  float inv[16];
#pragma unroll
  for (int r = 0; r < 16; ++r) inv[r] = 1.0f / rs[r];

  // ctx store (bf16, [B,S,D] with heads packed)
  int b = bh >> 4, h = bh & 15;
#pragma unroll
  for (int r = 0; r < 16; ++r) {
    int q = qw + (r & 3) + 8 * (r >> 2) + 4 * hi;
    size_t base = (size_t)(b * NS + q) * ND + h * NHD;
    Cb[base + lo] = (short)f2bf(c0[r] * inv[r]);
    Cb[base + 32 + lo] = (short)f2bf(c1[r] * inv[r]);
  }

  // ---------------- Sweep 2: write normalized attention weights ----------------
  for (int kt = 0; kt < 32; ++kt) {
    stageKV(kt, false);
    __syncthreads();
    f32x16 s0 = zero16(), s1 = zero16();
    scores(s0, s1);
#pragma unroll
    for (int r = 0; r < 16; ++r) {
      int qrow = (r & 3) + 8 * (r >> 2) + 4 * hi;
      float* arow = attnw + ((size_t)bh * NS + (qw + qrow)) * NS + kt * 64;
      arow[lo] = EXP2(s0[r]) * inv[r];
      arow[32 + lo] = EXP2(s1[r]) * inv[r];
    }
    __syncthreads();
  }
}

// ---------------------------------------------------------------------------
extern "C" void kernel_launch(void* const* d_in, const int* in_sizes, int n_in,
                              void* d_out, int out_size, void* d_ws, size_t ws_size,
                              hipStream_t stream) {
  const float* query = (const float*)d_in[0];
  const float* key = (const float*)d_in[1];
  const float* value = (const float*)d_in[2];
  const float* Wq = (const float*)d_in[3];
  const float* bq = (const float*)d_in[4];
  const float* Wk = (const float*)d_in[5];
  const float* bk = (const float*)d_in[6];
  const float* Wv = (const float*)d_in[7];
  const float* bv = (const float*)d_in[8];
  const float* Wo = (const float*)d_in[9];
  const float* bo = (const float*)d_in[10];

  float* out = (float*)d_out;                       // [B,S,D]
  float* attnw = out + (size_t)NB * NS * ND;        // [B,H,S,S]

  short* Qb = (short*)d_ws;                         // bf16 [B,H,S,HD], scaled
  short* Kb = Qb + (size_t)NB * NS * ND;            // bf16 [B,H,S,HD]
  short* Vt = Kb + (size_t)NB * NS * ND;            // bf16 [B,H,HD,S]
  short* Cb = Vt + (size_t)NB * NS * ND;            // bf16 [B*S, D] ctx
  short* WtQ = Cb + (size_t)NB * NS * ND;           // bf16 [N][K] each
  short* WtK = WtQ + (size_t)ND * ND;
  short* WtV = WtK + (size_t)ND * ND;
  short* WtO = WtV + (size_t)ND * ND;

  TWArgs tw;
  tw.W[0] = Wq; tw.W[1] = Wk; tw.W[2] = Wv; tw.W[3] = Wo;
  tw.Wt[0] = WtQ; tw.Wt[1] = WtK; tw.Wt[2] = WtV; tw.Wt[3] = WtO;
  wt_kernel<<<dim3(32, 32, 4), dim3(32, 8), 0, stream>>>(tw);

  ProjArgs pa;
  pa.A[0] = query; pa.A[1] = key; pa.A[2] = value;
  pa.W[0] = WtQ; pa.W[1] = WtK; pa.W[2] = WtV;
  pa.bias[0] = bq; pa.bias[1] = bk; pa.bias[2] = bv;
  pa.out[0] = Qb; pa.out[1] = Kb; pa.out[2] = Vt;
  pa.scale[0] = Q_SCALE; pa.scale[1] = 1.f; pa.scale[2] = 1.f;
  pa.mode[0] = 0; pa.mode[1] = 0; pa.mode[2] = 1;
  gemm_proj<false><<<dim3(256, 3), dim3(256), 0, stream>>>(pa);

  attn_kernel<<<dim3(16, 32), dim3(256), 0, stream>>>(Qb, Kb, Vt, Cb, attnw);

  ProjArgs po;
  po.A[0] = Cb; po.A[1] = Cb; po.A[2] = Cb;
  po.W[0] = WtO; po.W[1] = WtO; po.W[2] = WtO;
  po.bias[0] = bo; po.bias[1] = bo; po.bias[2] = bo;
  po.out[0] = out; po.out[1] = out; po.out[2] = out;
  po.scale[0] = 1.f; po.scale[1] = 1.f; po.scale[2] = 1.f;
  po.mode[0] = 2; po.mode[1] = 2; po.mode[2] = 2;
  gemm_proj<true><<<dim3(256, 1), dim3(256), 0, stream>>>(po);
}

// Round 3
// 765.797 us; speedup vs baseline: 1.0386x; 1.0386x over previous
//
#include <hip/hip_runtime.h>
#include <hip/hip_bf16.h>

typedef __attribute__((ext_vector_type(4)))  float  f32x4;
typedef __attribute__((ext_vector_type(16))) float  f32x16;
typedef __attribute__((ext_vector_type(4)))  float  floatv4;
typedef __attribute__((ext_vector_type(8)))  short  short8;
typedef __attribute__((ext_vector_type(8)))  __bf16 bf16x8;

#define NB 2
#define NS 2048
#define ND 1024
#define NH 16
#define NHD 64
// (1/8) * log2(e): folds both the attention scale and the exp->exp2 base change into Q
#define Q_SCALE 0.18033688011112042f

#if __has_builtin(__builtin_amdgcn_exp2f)
#define EXP2(x) __builtin_amdgcn_exp2f(x)
#else
#define EXP2(x) exp2f(x)
#endif

// native RNE f32->bf16 (compiler pairs these into v_cvt_pk_bf16_f32)
static __device__ __forceinline__ short bfc(float f) {
  return __builtin_bit_cast(short, (__bf16)f);
}

static __device__ __forceinline__ f32x4 mfma16(short8 a, short8 b, f32x4 c) {
  return __builtin_amdgcn_mfma_f32_16x16x32_bf16(
      __builtin_bit_cast(bf16x8, a), __builtin_bit_cast(bf16x8, b), c, 0, 0, 0);
}
static __device__ __forceinline__ f32x16 mfma32(short8 a, short8 b, f32x16 c) {
  return __builtin_amdgcn_mfma_f32_32x32x16_bf16(
      __builtin_bit_cast(bf16x8, a), __builtin_bit_cast(bf16x8, b), c, 0, 0, 0);
}

static __device__ __forceinline__ f32x16 zero16() {
  f32x16 z;
#pragma unroll
  for (int i = 0; i < 16; ++i) z[i] = 0.f;
  return z;
}

// ---------------------------------------------------------------------------
// Weight transpose + bf16 convert: Wt[n][k] = bf16(W[k][n])
// ---------------------------------------------------------------------------
struct TWArgs { const float* W[4]; short* Wt[4]; };

__global__ __launch_bounds__(256) void wt_kernel(TWArgs args) {
  __shared__ float tile[32][33];
  const float* W = args.W[blockIdx.z];
  short* Wt = args.Wt[blockIdx.z];
  int k0 = blockIdx.x * 32, n0 = blockIdx.y * 32;
  int tx = threadIdx.x, ty = threadIdx.y;  // 32 x 8
#pragma unroll
  for (int i = 0; i < 4; ++i)
    tile[ty + 8 * i][tx] = W[(size_t)(k0 + ty + 8 * i) * ND + n0 + tx];
  __syncthreads();
#pragma unroll
  for (int i = 0; i < 4; ++i)
    Wt[(size_t)(n0 + ty + 8 * i) * ND + k0 + tx] = bfc(tile[tx][ty + 8 * i]);
}

// ---------------------------------------------------------------------------
// Projection GEMM: C[M=4096, N=1024] = A[4096,1024] @ W(K,N) + bias
// Wt given transposed bf16 [N][K]. BM=BN=128, BK=32, 4 waves (2x2), 16x16x32 MFMA.
// mode 0: bf16 out [B][H][S][HD] (Q/K layout), * scale after bias
// mode 1: bf16 out [B][H][HD][S] (V transposed layout)
// mode 2: f32 out flat [M][N]    (final output)
// ---------------------------------------------------------------------------
struct ProjArgs {
  const void* A[3]; const short* W[3]; const float* bias[3];
  void* out[3]; float scale[3]; int mode[3];
};

template<bool A_BF16>
__global__ __launch_bounds__(256, 3) void gemm_proj(ProjArgs args) {
  int z = blockIdx.y;
  const char* Abase = (const char*)args.A[z];
  const short* W = args.W[z];
  const float* bias = args.bias[z];
  float scale = args.scale[z];
  int mode = args.mode[z];

  __shared__ short As[128 * 32];
  __shared__ short Bs[128 * 32];
  int tid = threadIdx.x;
  int lane = tid & 63;
  int wave = tid >> 6;
  int wr = wave >> 1, wc = wave & 1;
  int m0 = (blockIdx.x >> 3) * 128;
  int n0 = (blockIdx.x & 7) * 128;

  int srow = tid >> 1, shalf = tid & 1;
  unsigned sbase = (unsigned)(srow * 64 + shalf * 32);
  unsigned ssw = ((unsigned)(srow & 7)) << 4;
  unsigned d1 = sbase ^ ssw, d2 = (sbase + 16u) ^ ssw;

  f32x4 acc[4][4];
#pragma unroll
  for (int i = 0; i < 4; ++i)
#pragma unroll
    for (int j = 0; j < 4; ++j) acc[i][j] = (f32x4){0.f, 0.f, 0.f, 0.f};

  for (int kt = 0; kt < 32; ++kt) {
    int k0 = kt * 32;
    // --- stage A tile (rows m0..m0+127, k0..k0+31) ---
    if (A_BF16) {
      const short* src = (const short*)Abase + (size_t)(m0 + srow) * ND + k0 + shalf * 16;
      short8 v0 = ((const short8*)src)[0];
      short8 v1 = ((const short8*)src)[1];
      *(short8*)((char*)As + d1) = v0;
      *(short8*)((char*)As + d2) = v1;
    } else {
      const float* src = (const float*)Abase + (size_t)(m0 + srow) * ND + k0 + shalf * 16;
      floatv4 f0 = ((const floatv4*)src)[0];
      floatv4 f1 = ((const floatv4*)src)[1];
      floatv4 f2 = ((const floatv4*)src)[2];
      floatv4 f3 = ((const floatv4*)src)[3];
      short8 v0, v1;
#pragma unroll
      for (int j = 0; j < 4; ++j) { v0[j] = bfc(f0[j]); v0[4 + j] = bfc(f1[j]); }
#pragma unroll
      for (int j = 0; j < 4; ++j) { v1[j] = bfc(f2[j]); v1[4 + j] = bfc(f3[j]); }
      *(short8*)((char*)As + d1) = v0;
      *(short8*)((char*)As + d2) = v1;
    }
    // --- stage B tile (Wt rows n0..n0+127, k0..k0+31) ---
    {
      const short* src = W + (size_t)(n0 + srow) * ND + k0 + shalf * 16;
      short8 v0 = ((const short8*)src)[0];
      short8 v1 = ((const short8*)src)[1];
      *(short8*)((char*)Bs + d1) = v0;
      *(short8*)((char*)Bs + d2) = v1;
    }
    __syncthreads();

    short8 af[4], bfr[4];
#pragma unroll
    for (int i = 0; i < 4; ++i) {
      int row = wr * 64 + i * 16 + (lane & 15);
      unsigned bo = ((unsigned)(row * 64 + (lane >> 4) * 16)) ^ (((unsigned)(row & 7)) << 4);
      af[i] = *(const short8*)((const char*)As + bo);
      int col = wc * 64 + i * 16 + (lane & 15);
      unsigned bo2 = ((unsigned)(col * 64 + (lane >> 4) * 16)) ^ (((unsigned)(col & 7)) << 4);
      bfr[i] = *(const short8*)((const char*)Bs + bo2);
    }
#pragma unroll
    for (int i = 0; i < 4; ++i)
#pragma unroll
      for (int j = 0; j < 4; ++j)
        acc[i][j] = mfma16(af[i], bfr[j], acc[i][j]);
    __syncthreads();
  }

  // --- epilogue ---
#pragma unroll
  for (int j = 0; j < 4; ++j) {
    int n = n0 + wc * 64 + j * 16 + (lane & 15);
    float bv = bias[n];
#pragma unroll
    for (int i = 0; i < 4; ++i) {
#pragma unroll
      for (int r = 0; r < 4; ++r) {
        int m = m0 + wr * 64 + i * 16 + (lane >> 4) * 4 + r;
        float v = (acc[i][j][r] + bv) * scale;
        if (mode == 2) {
          ((float*)args.out[z])[(size_t)m * ND + n] = v;
        } else {
          int b = m >> 11, s = m & 2047, h = n >> 6, d = n & 63;
          size_t idx = (mode == 0)
                           ? (((size_t)(b * NH + h) * NS + s) * NHD + d)
                           : (((size_t)(b * NH + h) * NHD + d) * NS + s);
          ((short*)args.out[z])[idx] = bfc(v);
        }
      }
    }
  }
}

// ---------------------------------------------------------------------------
// Fused attention: per WG (q-tile of 128 rows, one (b,h)); 4 waves x 32 q-rows.
// Sweep 1: e = exp2(Q.K'), rowsum, unnormalized PV (P via swizzled LDS transpose).
// Sweep 2: recompute scores, write p = e * inv_rowsum to attn output (512 MB, once).
// K/V tiles double-buffered: global->reg issued during compute(t), reg->LDS written
// after the barrier (T14 issue-early/write-late) so HBM latency hides under MFMA.
// ---------------------------------------------------------------------------
__global__ __launch_bounds__(256, 2) void attn_kernel(
    const short* __restrict__ Qb, const short* __restrict__ Kb,
    const short* __restrict__ Vt, short* __restrict__ Cb,
    float* __restrict__ attnw) {
  __shared__ short Ks[2][64 * 64];
  __shared__ short Vs[2][64 * 64];
  __shared__ short Ps[4][32 * 64];
  int bh = blockIdx.y;
  int q0 = blockIdx.x * 128;
  int tid = threadIdx.x;
  int wave = tid >> 6, lane = tid & 63;
  int lo = lane & 31, hi = lane >> 5;
  const short* Qh = Qb + (size_t)bh * NS * NHD;
  const short* Kh = Kb + (size_t)bh * NS * NHD;
  const short* Vh = Vt + (size_t)bh * NHD * NS;
  int qw = q0 + wave * 32;

  short8 aq[4];
#pragma unroll
  for (int ks = 0; ks < 4; ++ks)
    aq[ks] = *(const short8*)(Qh + (size_t)(qw + lo) * NHD + ks * 16 + hi * 8);

  float rs[16];
#pragma unroll
  for (int r = 0; r < 16; ++r) rs[r] = 0.f;
  f32x16 c0 = zero16(), c1 = zero16();

  char* PsW = (char*)Ps[wave];

  // staging geometry (thread-constant)
  int srow = tid >> 3, soff = tid & 7;            // rows 0..31 (+32 for second chunk)
  unsigned dst0 = ((unsigned)(srow * 128 + soff * 16)) ^ (((unsigned)(srow & 7)) << 4);
  unsigned dst1 = ((unsigned)((srow + 32) * 128 + soff * 16)) ^ (((unsigned)((srow + 32) & 7)) << 4);

  short8 kA, kB, vA, vB;
  auto loadKV = [&](int kt, bool withV) {
    kA = *(const short8*)(Kh + (size_t)(kt * 64 + srow) * NHD + soff * 8);
    kB = *(const short8*)(Kh + (size_t)(kt * 64 + srow + 32) * NHD + soff * 8);
    if (withV) {
      vA = *(const short8*)(Vh + (size_t)srow * NS + kt * 64 + soff * 8);
      vB = *(const short8*)(Vh + (size_t)(srow + 32) * NS + kt * 64 + soff * 8);
    }
  };
  auto writeKV = [&](int cur, bool withV) {
    *(short8*)((char*)Ks[cur] + dst0) = kA;
    *(short8*)((char*)Ks[cur] + dst1) = kB;
    if (withV) {
      *(short8*)((char*)Vs[cur] + dst0) = vA;
      *(short8*)((char*)Vs[cur] + dst1) = vB;
    }
  };

  auto scores = [&](int cur, f32x16& s0, f32x16& s1) {
#pragma unroll
    for (int ks = 0; ks < 4; ++ks) {
      unsigned ko = (unsigned)(ks * 32 + hi * 16);
      unsigned sw = ((unsigned)(lo & 7)) << 4;
      short8 bk0 = *(const short8*)((const char*)Ks[cur] + (((unsigned)(lo * 128) + ko) ^ sw));
      short8 bk1 = *(const short8*)((const char*)Ks[cur] + (((unsigned)((lo + 32) * 128) + ko) ^ sw));
      s0 = mfma32(aq[ks], bk0, s0);
      s1 = mfma32(aq[ks], bk1, s1);
    }
  };

  // ---------------- Sweep 1 ----------------
  loadKV(0, true);
  for (int kt = 0; kt < 32; ++kt) {
    int cur = kt & 1;
    writeKV(cur, true);
    if (kt + 1 < 32) loadKV(kt + 1, true);   // prefetch next tile (in flight across barrier)
    __syncthreads();
    f32x16 s0 = zero16(), s1 = zero16();
    scores(cur, s0, s1);
#pragma unroll
    for (int r = 0; r < 16; ++r) {
      float e0 = EXP2(s0[r]);
      float e1 = EXP2(s1[r]);
      rs[r] += e0 + e1;
      int qrow = (r & 3) + 8 * (r >> 2) + 4 * hi;
      unsigned sw = ((unsigned)(qrow & 7)) << 4;
      *(short*)(PsW + (((unsigned)(qrow * 128 + lo * 2)) ^ sw)) = bfc(e0);
      *(short*)(PsW + (((unsigned)(qrow * 128 + 64 + lo * 2)) ^ sw)) = bfc(e1);
    }
    asm volatile("s_waitcnt lgkmcnt(0)" ::: "memory");
    // PV: ctx += P * V  (A = P rows q, B = Vt rows d)
#pragma unroll
    for (int kk = 0; kk < 4; ++kk) {
      unsigned ko = (unsigned)(kk * 32 + hi * 16);
      unsigned sw = ((unsigned)(lo & 7)) << 4;
      short8 ap = *(const short8*)(PsW + (((unsigned)(lo * 128) + ko) ^ sw));
      short8 bv0 = *(const short8*)((const char*)Vs[cur] + (((unsigned)(lo * 128) + ko) ^ sw));
      short8 bv1 = *(const short8*)((const char*)Vs[cur] + (((unsigned)((lo + 32) * 128) + ko) ^ sw));
      c0 = mfma32(ap, bv0, c0);
      c1 = mfma32(ap, bv1, c1);
    }
    __syncthreads();
  }

  // rowsum reduce across the 32 lanes sharing the same q-row set
#pragma unroll
  for (int r = 0; r < 16; ++r) {
    float v = rs[r];
    v += __shfl_xor(v, 1);
    v += __shfl_xor(v, 2);
    v += __shfl_xor(v, 4);
    v += __shfl_xor(v, 8);
    v += __shfl_xor(v, 16);
    rs[r] = v;
  }
  float inv[16];
#pragma unroll
  for (int r = 0; r < 16; ++r) inv[r] = 1.0f / rs[r];

  // ctx store (bf16, [B,S,D] with heads packed)
  int b = bh >> 4, h = bh & 15;
#pragma unroll
  for (int r = 0; r < 16; ++r) {
    int q = qw + (r & 3) + 8 * (r >> 2) + 4 * hi;
    size_t base = (size_t)(b * NS + q) * ND + h * NHD;
    Cb[base + lo] = bfc(c0[r] * inv[r]);
    Cb[base + 32 + lo] = bfc(c1[r] * inv[r]);
  }

  // ---------------- Sweep 2: write normalized attention weights ----------------
  loadKV(0, false);
  for (int kt = 0; kt < 32; ++kt) {
    int cur = kt & 1;
    writeKV(cur, false);
    if (kt + 1 < 32) loadKV(kt + 1, false);
    __syncthreads();
    f32x16 s0 = zero16(), s1 = zero16();
    scores(cur, s0, s1);
#pragma unroll
    for (int r = 0; r < 16; ++r) {
      int qrow = (r & 3) + 8 * (r >> 2) + 4 * hi;
      float* arow = attnw + ((size_t)bh * NS + (qw + qrow)) * NS + kt * 64;
      arow[lo] = EXP2(s0[r]) * inv[r];
      arow[32 + lo] = EXP2(s1[r]) * inv[r];
    }
    __syncthreads();
  }
}

// ---------------------------------------------------------------------------
extern "C" void kernel_launch(void* const* d_in, const int* in_sizes, int n_in,
                              void* d_out, int out_size, void* d_ws, size_t ws_size,
                              hipStream_t stream) {
  const float* query = (const float*)d_in[0];
  const float* key = (const float*)d_in[1];
  const float* value = (const float*)d_in[2];
  const float* Wq = (const float*)d_in[3];
  const float* bq = (const float*)d_in[4];
  const float* Wk = (const float*)d_in[5];
  const float* bk = (const float*)d_in[6];
  const float* Wv = (const float*)d_in[7];
  const float* bv = (const float*)d_in[8];
  const float* Wo = (const float*)d_in[9];
  const float* bo = (const float*)d_in[10];

  float* out = (float*)d_out;                       // [B,S,D]
  float* attnw = out + (size_t)NB * NS * ND;        // [B,H,S,S]

  short* Qb = (short*)d_ws;                         // bf16 [B,H,S,HD], scaled
  short* Kb = Qb + (size_t)NB * NS * ND;            // bf16 [B,H,S,HD]
  short* Vt = Kb + (size_t)NB * NS * ND;            // bf16 [B,H,HD,S]
  short* Cb = Vt + (size_t)NB * NS * ND;            // bf16 [B*S, D] ctx
  short* WtQ = Cb + (size_t)NB * NS * ND;           // bf16 [N][K] each
  short* WtK = WtQ + (size_t)ND * ND;
  short* WtV = WtK + (size_t)ND * ND;
  short* WtO = WtV + (size_t)ND * ND;

  TWArgs tw;
  tw.W[0] = Wq; tw.W[1] = Wk; tw.W[2] = Wv; tw.W[3] = Wo;
  tw.Wt[0] = WtQ; tw.Wt[1] = WtK; tw.Wt[2] = WtV; tw.Wt[3] = WtO;
  wt_kernel<<<dim3(32, 32, 4), dim3(32, 8), 0, stream>>>(tw);

  ProjArgs pa;
  pa.A[0] = query; pa.A[1] = key; pa.A[2] = value;
  pa.W[0] = WtQ; pa.W[1] = WtK; pa.W[2] = WtV;
  pa.bias[0] = bq; pa.bias[1] = bk; pa.bias[2] = bv;
  pa.out[0] = Qb; pa.out[1] = Kb; pa.out[2] = Vt;
  pa.scale[0] = Q_SCALE; pa.scale[1] = 1.f; pa.scale[2] = 1.f;
  pa.mode[0] = 0; pa.mode[1] = 0; pa.mode[2] = 1;
  gemm_proj<false><<<dim3(256, 3), dim3(256), 0, stream>>>(pa);

  attn_kernel<<<dim3(16, 32), dim3(256), 0, stream>>>(Qb, Kb, Vt, Cb, attnw);

  ProjArgs po;
  po.A[0] = Cb; po.A[1] = Cb; po.A[2] = Cb;
  po.W[0] = WtO; po.W[1] = WtO; po.W[2] = WtO;
  po.bias[0] = bo; po.bias[1] = bo; po.bias[2] = bo;
  po.out[0] = out; po.out[1] = out; po.out[2] = out;
  po.scale[0] = 1.f; po.scale[1] = 1.f; po.scale[2] = 1.f;
  po.mode[0] = 2; po.mode[1] = 2; po.mode[2] = 2;
  gemm_proj<true><<<dim3(256, 1), dim3(256), 0, stream>>>(po);
}